// Round 5
// baseline (105.314 us; speedup 1.0000x reference)
//
#include <hip/hip_runtime.h>
#include <hip/hip_cooperative_groups.h>
#include <math.h>

#define N_NODES 100000
#define N_EDGES 600000
#define IN_CH 128
#define HID 64
#define NEG_SLOPE 0.01f

typedef float4 f4;
typedef unsigned short u16;
typedef unsigned int u32;
typedef __attribute__((ext_vector_type(8))) short bf16x8;   // 8 bf16 (4 VGPRs)
typedef __attribute__((ext_vector_type(4))) float f32x4;    // MFMA acc

__device__ __forceinline__ float lrelu(float x) {
    return fmaxf(x, NEG_SLOPE * x);
}
__device__ __forceinline__ float uasf(u32 w) { return __uint_as_float(w); }

// HW packed conversion: one VALU op for 2 f32 -> packed bf16.
__device__ __forceinline__ u32 cvt_pk(float lo, float hi) {
    u32 r;
    asm("v_cvt_pk_bf16_f32 %0, %1, %2" : "=v"(r) : "v"(lo), "v"(hi));
    return r;
}

__device__ __forceinline__ int load_idx(const void* ei, int is64, int pos) {
    if (is64) return (int)((const long long*)ei)[pos];
    return ((const int*)ei)[pos];
}

// shared edge dot: 8 bf16 pairs vs W2 chunk
__device__ __forceinline__ float edot(uint4 a, uint4 b, f4 w0, f4 w1) {
    float s;
    s  = lrelu(uasf(a.x << 16) + uasf(b.x << 16)) * w0.x;
    s += lrelu(uasf(a.x & 0xffff0000u) + uasf(b.x & 0xffff0000u)) * w0.y;
    s += lrelu(uasf(a.y << 16) + uasf(b.y << 16)) * w0.z;
    s += lrelu(uasf(a.y & 0xffff0000u) + uasf(b.y & 0xffff0000u)) * w0.w;
    s += lrelu(uasf(a.z << 16) + uasf(b.z << 16)) * w1.x;
    s += lrelu(uasf(a.z & 0xffff0000u) + uasf(b.z & 0xffff0000u)) * w1.y;
    s += lrelu(uasf(a.w << 16) + uasf(b.w << 16)) * w1.z;
    s += lrelu(uasf(a.w & 0xffff0000u) + uasf(b.w & 0xffff0000u)) * w1.w;
    return s;
}

// ---------------------------------------------------------------------------
// FUSED cooperative kernel.
// Phase 1 (grid-stride over 64-node tiles): MFMA node projection into pcomb
//   (bf16, row = [pl(64) | pr(64)]). Same verified layout/swizzle as round 3/4
//   (absmax 3.9e-3): acc = mfma(W_frag, z_frag, acc); XOR-swizzled LDS slot
//   (row<<4)|(gr^(row&15)); K-slot bijection gran=(kk<<2)|g shared by both
//   operands.
// grid.sync()
// Phase 2 (grid-stride over edge quads): 8 lanes per quad of 4 edges; lane c
//   gathers 16B chunk c of pl[src] / chunk 8+c of pr[dst]; 8 gathers in
//   flight/thread; width-8 shfl reduce; lane 0 writes float4 of sigmoids.
// Per-block is64 detect (LDS atomicOr over high words of first 2048 entries).
// ---------------------------------------------------------------------------
__global__ __launch_bounds__(256) void fused_kernel(
    const float* __restrict__ z, const float* __restrict__ W1l,
    const float* __restrict__ b1l, const float* __restrict__ W1r,
    const float* __restrict__ b1r, const void* __restrict__ ei,
    const float* __restrict__ W2, const float* __restrict__ b2,
    float* __restrict__ out, u16* __restrict__ pcomb) {
    __shared__ uint4 wt[128 * 16];  // 32 KB
    __shared__ uint4 zt[64 * 16];   // 16 KB
    __shared__ u32 sflag;

    const int tid = threadIdx.x;

    // is64 detect: OR of high words of first 2048 8-byte entries
    if (tid == 0) sflag = 0u;
    __syncthreads();
    {
        u32 acc = 0u;
        const u32* w = (const u32*)ei;
        #pragma unroll
        for (int i = 0; i < 8; ++i) acc |= w[(i * 256 + tid) * 2 + 1];
        if (acc) atomicOr(&sflag, 1u);
    }

    // stage W_comb as bf16, swizzled (once per block)
    #pragma unroll
    for (int i = 0; i < 8; ++i) {
        int gidx = tid + i * 256;        // row*16 + gr
        int row = gidx >> 4, gr = gidx & 15;
        const float* wsrc = (row < 64) ? (W1l + row * IN_CH)
                                       : (W1r + (row - 64) * IN_CH);
        f4 a = ((const f4*)wsrc)[gr * 2];
        f4 b = ((const f4*)wsrc)[gr * 2 + 1];
        uint4 p;
        p.x = cvt_pk(a.x, a.y); p.y = cvt_pk(a.z, a.w);
        p.z = cvt_pk(b.x, b.y); p.w = cvt_pk(b.z, b.w);
        wt[(row << 4) | (gr ^ (row & 15))] = p;
    }

    const int wave = tid >> 6, lane = tid & 63;
    const int m = lane & 15, g = lane >> 4;

    // ---- Phase 1: node projection ----
    for (int tile = blockIdx.x; tile * 64 < N_NODES; tile += gridDim.x) {
        const int base = tile * 64;
        #pragma unroll
        for (int i = 0; i < 4; ++i) {
            int gidx = tid + i * 256;
            int row = gidx >> 4, gr = gidx & 15;
            int node = base + row;
            if (node >= N_NODES) node = N_NODES - 1;  // pad reads
            f4 a = ((const f4*)z)[node * 32 + gr * 2];
            f4 b = ((const f4*)z)[node * 32 + gr * 2 + 1];
            uint4 p;
            p.x = cvt_pk(a.x, a.y); p.y = cvt_pk(a.z, a.w);
            p.z = cvt_pk(b.x, b.y); p.w = cvt_pk(b.z, b.w);
            zt[(row << 4) | (gr ^ (row & 15))] = p;
        }
        __syncthreads();

        f32x4 acc[4][2];
        #pragma unroll
        for (int n4 = 0; n4 < 4; ++n4)
            #pragma unroll
            for (int c2 = 0; c2 < 2; ++c2) acc[n4][c2] = {0.f, 0.f, 0.f, 0.f};

        #pragma unroll
        for (int kk = 0; kk < 4; ++kk) {
            const int gran = (kk << 2) | g;
            bf16x8 zf[4], wf[2];
            #pragma unroll
            for (int n4 = 0; n4 < 4; ++n4)
                zf[n4] = *(const bf16x8*)&zt[(((n4 << 4) | m) << 4) | (gran ^ m)];
            #pragma unroll
            for (int c2 = 0; c2 < 2; ++c2) {
                int R = (wave << 5) + (c2 << 4) + m;
                wf[c2] = *(const bf16x8*)&wt[(R << 4) | (gran ^ m)];
            }
            #pragma unroll
            for (int n4 = 0; n4 < 4; ++n4)
                #pragma unroll
                for (int c2 = 0; c2 < 2; ++c2)
                    acc[n4][c2] = __builtin_amdgcn_mfma_f32_16x16x32_bf16(
                        wf[c2], zf[n4], acc[n4][c2], 0, 0, 0);
        }

        const int colbase = wave << 5;
        #pragma unroll
        for (int c2 = 0; c2 < 2; ++c2) {
            const int col0 = colbase + (c2 << 4) + (g << 2);
            const float* bsrc = (colbase < 64) ? (b1l + col0) : (b1r + col0 - 64);
            f4 bb = *(const f4*)bsrc;
            #pragma unroll
            for (int n4 = 0; n4 < 4; ++n4) {
                int node = base + (n4 << 4) + m;
                if (node < N_NODES) {
                    uint2 v;
                    v.x = cvt_pk(acc[n4][c2][0] + bb.x, acc[n4][c2][1] + bb.y);
                    v.y = cvt_pk(acc[n4][c2][2] + bb.z, acc[n4][c2][3] + bb.w);
                    *(uint2*)(pcomb + (size_t)node * 128 + col0) = v;
                }
            }
        }
        __syncthreads();  // zt safe to overwrite next tile
    }

    const int is64 = (sflag == 0u);

    cooperative_groups::this_grid().sync();

    // ---- Phase 2: edges, 4 per 8-lane slot thread ----
    const int c = tid & 7;
    const f4 w0 = ((const f4*)W2)[c * 2];
    const f4 w1 = ((const f4*)W2)[c * 2 + 1];
    const float bb = b2[0];
    const int nthreads = gridDim.x * 256;
    const int qstride = nthreads >> 3;
    const int NQ = N_EDGES / 4;  // 150000 quads

    for (int q = (blockIdx.x * 256 + tid) >> 3; q < NQ; q += qstride) {
        int s[4], d[4];
        if (is64) {
            const longlong2* p = (const longlong2*)ei;
            longlong2 p0 = p[2 * q], p1 = p[2 * q + 1];
            longlong2 q0 = p[N_EDGES / 2 + 2 * q], q1 = p[N_EDGES / 2 + 2 * q + 1];
            s[0] = (int)p0.x; s[1] = (int)p0.y; s[2] = (int)p1.x; s[3] = (int)p1.y;
            d[0] = (int)q0.x; d[1] = (int)q0.y; d[2] = (int)q1.x; d[3] = (int)q1.y;
        } else {
            int4 sp = ((const int4*)ei)[q];
            int4 dp = ((const int4*)ei)[N_EDGES / 4 + q];
            s[0] = sp.x; s[1] = sp.y; s[2] = sp.z; s[3] = sp.w;
            d[0] = dp.x; d[1] = dp.y; d[2] = dp.z; d[3] = dp.w;
        }
        const uint4* pc4 = (const uint4*)pcomb;
        uint4 a0 = pc4[s[0] * 16 + c],     a1 = pc4[s[1] * 16 + c];
        uint4 a2 = pc4[s[2] * 16 + c],     a3 = pc4[s[3] * 16 + c];
        uint4 e0 = pc4[d[0] * 16 + 8 + c], e1 = pc4[d[1] * 16 + 8 + c];
        uint4 e2 = pc4[d[2] * 16 + 8 + c], e3 = pc4[d[3] * 16 + 8 + c];
        float r0 = edot(a0, e0, w0, w1);
        float r1 = edot(a1, e1, w0, w1);
        float r2 = edot(a2, e2, w0, w1);
        float r3 = edot(a3, e3, w0, w1);
        #pragma unroll
        for (int off = 4; off; off >>= 1) {
            r0 += __shfl_xor(r0, off, 8);
            r1 += __shfl_xor(r1, off, 8);
            r2 += __shfl_xor(r2, off, 8);
            r3 += __shfl_xor(r3, off, 8);
        }
        if (c == 0) {
            f4 o;
            o.x = 1.f / (1.f + __expf(-(r0 + bb)));
            o.y = 1.f / (1.f + __expf(-(r1 + bb)));
            o.z = 1.f / (1.f + __expf(-(r2 + bb)));
            o.w = 1.f / (1.f + __expf(-(r3 + bb)));
            *(f4*)(out + q * 4) = o;
        }
    }
}

// ---------------------------------------------------------------------------
// Fallback two-kernel path (round-4 proven, 45.7 us) — used if cooperative
// launch is rejected.
// ---------------------------------------------------------------------------
__global__ __launch_bounds__(256) void node_proj_kernel(
    const float* __restrict__ z, const float* __restrict__ W1l,
    const float* __restrict__ b1l, const float* __restrict__ W1r,
    const float* __restrict__ b1r, const u32* __restrict__ ei_words,
    int* __restrict__ flag, u16* __restrict__ pcomb) {
    __shared__ uint4 wt[128 * 16];
    __shared__ uint4 zt[64 * 16];
    __shared__ u32 red;

    const int tid = threadIdx.x;

    if (blockIdx.x == 0) {
        if (tid == 0) red = 0u;
        __syncthreads();
        u32 acc = 0u;
        #pragma unroll
        for (int i = 0; i < 8; ++i)
            acc |= ei_words[(i * 256 + tid) * 2 + 1];
        atomicOr(&red, acc);
        __syncthreads();
        if (tid == 0) *flag = (red == 0u) ? 1 : 0;
    }

    #pragma unroll
    for (int i = 0; i < 8; ++i) {
        int gidx = tid + i * 256;
        int row = gidx >> 4, gr = gidx & 15;
        const float* wsrc = (row < 64) ? (W1l + row * IN_CH)
                                       : (W1r + (row - 64) * IN_CH);
        f4 a = ((const f4*)wsrc)[gr * 2];
        f4 b = ((const f4*)wsrc)[gr * 2 + 1];
        uint4 p;
        p.x = cvt_pk(a.x, a.y); p.y = cvt_pk(a.z, a.w);
        p.z = cvt_pk(b.x, b.y); p.w = cvt_pk(b.z, b.w);
        wt[(row << 4) | (gr ^ (row & 15))] = p;
    }

    const int base = blockIdx.x * 64;
    #pragma unroll
    for (int i = 0; i < 4; ++i) {
        int gidx = tid + i * 256;
        int row = gidx >> 4, gr = gidx & 15;
        int node = base + row;
        if (node >= N_NODES) node = N_NODES - 1;
        f4 a = ((const f4*)z)[node * 32 + gr * 2];
        f4 b = ((const f4*)z)[node * 32 + gr * 2 + 1];
        uint4 p;
        p.x = cvt_pk(a.x, a.y); p.y = cvt_pk(a.z, a.w);
        p.z = cvt_pk(b.x, b.y); p.w = cvt_pk(b.z, b.w);
        zt[(row << 4) | (gr ^ (row & 15))] = p;
    }
    __syncthreads();

    const int wave = tid >> 6, lane = tid & 63;
    const int m = lane & 15, g = lane >> 4;

    f32x4 acc[4][2];
    #pragma unroll
    for (int n4 = 0; n4 < 4; ++n4)
        #pragma unroll
        for (int c2 = 0; c2 < 2; ++c2) acc[n4][c2] = {0.f, 0.f, 0.f, 0.f};

    #pragma unroll
    for (int kk = 0; kk < 4; ++kk) {
        const int gran = (kk << 2) | g;
        bf16x8 zf[4], wf[2];
        #pragma unroll
        for (int n4 = 0; n4 < 4; ++n4)
            zf[n4] = *(const bf16x8*)&zt[(((n4 << 4) | m) << 4) | (gran ^ m)];
        #pragma unroll
        for (int c2 = 0; c2 < 2; ++c2) {
            int R = (wave << 5) + (c2 << 4) + m;
            wf[c2] = *(const bf16x8*)&wt[(R << 4) | (gran ^ m)];
        }
        #pragma unroll
        for (int n4 = 0; n4 < 4; ++n4)
            #pragma unroll
            for (int c2 = 0; c2 < 2; ++c2)
                acc[n4][c2] = __builtin_amdgcn_mfma_f32_16x16x32_bf16(
                    wf[c2], zf[n4], acc[n4][c2], 0, 0, 0);
    }

    const int colbase = wave << 5;
    #pragma unroll
    for (int c2 = 0; c2 < 2; ++c2) {
        const int col0 = colbase + (c2 << 4) + (g << 2);
        const float* bsrc = (colbase < 64) ? (b1l + col0) : (b1r + col0 - 64);
        f4 bb = *(const f4*)bsrc;
        #pragma unroll
        for (int n4 = 0; n4 < 4; ++n4) {
            int node = base + (n4 << 4) + m;
            if (node < N_NODES) {
                uint2 v;
                v.x = cvt_pk(acc[n4][c2][0] + bb.x, acc[n4][c2][1] + bb.y);
                v.y = cvt_pk(acc[n4][c2][2] + bb.z, acc[n4][c2][3] + bb.w);
                *(uint2*)(pcomb + (size_t)node * 128 + col0) = v;
            }
        }
    }
}

__global__ __launch_bounds__(256) void edge_quad_kernel(
    const void* __restrict__ ei, const int* __restrict__ flag,
    const u16* __restrict__ pcomb, const float* __restrict__ W2,
    const float* __restrict__ b2, float* __restrict__ out) {
    int t = blockIdx.x * 256 + threadIdx.x;
    int q = t >> 3;
    int c = t & 7;
    if (q >= N_EDGES / 4) return;
    const int is64 = *flag;
    int s[4], d[4];
    if (is64) {
        const longlong2* p = (const longlong2*)ei;
        longlong2 p0 = p[2 * q], p1 = p[2 * q + 1];
        longlong2 q0 = p[N_EDGES / 2 + 2 * q], q1 = p[N_EDGES / 2 + 2 * q + 1];
        s[0] = (int)p0.x; s[1] = (int)p0.y; s[2] = (int)p1.x; s[3] = (int)p1.y;
        d[0] = (int)q0.x; d[1] = (int)q0.y; d[2] = (int)q1.x; d[3] = (int)q1.y;
    } else {
        int4 sp = ((const int4*)ei)[q];
        int4 dp = ((const int4*)ei)[N_EDGES / 4 + q];
        s[0] = sp.x; s[1] = sp.y; s[2] = sp.z; s[3] = sp.w;
        d[0] = dp.x; d[1] = dp.y; d[2] = dp.z; d[3] = dp.w;
    }
    const uint4* pc4 = (const uint4*)pcomb;
    uint4 a0 = pc4[s[0] * 16 + c],     a1 = pc4[s[1] * 16 + c];
    uint4 a2 = pc4[s[2] * 16 + c],     a3 = pc4[s[3] * 16 + c];
    uint4 e0 = pc4[d[0] * 16 + 8 + c], e1 = pc4[d[1] * 16 + 8 + c];
    uint4 e2 = pc4[d[2] * 16 + 8 + c], e3 = pc4[d[3] * 16 + 8 + c];
    f4 w0 = ((const f4*)W2)[c * 2];
    f4 w1 = ((const f4*)W2)[c * 2 + 1];
    float r0 = edot(a0, e0, w0, w1);
    float r1 = edot(a1, e1, w0, w1);
    float r2 = edot(a2, e2, w0, w1);
    float r3 = edot(a3, e3, w0, w1);
    #pragma unroll
    for (int off = 4; off; off >>= 1) {
        r0 += __shfl_xor(r0, off, 8);
        r1 += __shfl_xor(r1, off, 8);
        r2 += __shfl_xor(r2, off, 8);
        r3 += __shfl_xor(r3, off, 8);
    }
    if (c == 0) {
        float bb = b2[0];
        f4 o;
        o.x = 1.f / (1.f + __expf(-(r0 + bb)));
        o.y = 1.f / (1.f + __expf(-(r1 + bb)));
        o.z = 1.f / (1.f + __expf(-(r2 + bb)));
        o.w = 1.f / (1.f + __expf(-(r3 + bb)));
        *(f4*)(out + q * 4) = o;
    }
}

// Tiny-workspace fallbacks (unchanged, proven)
__global__ void detect_idx_kernel(const u32* __restrict__ ei_words,
                                  int* __restrict__ flag) {
    __shared__ u32 red;
    if (threadIdx.x == 0) red = 0u;
    __syncthreads();
    u32 acc = 0u;
    #pragma unroll
    for (int i = 0; i < 8; ++i)
        acc |= ei_words[(i * 256 + threadIdx.x) * 2 + 1];
    atomicOr(&red, acc);
    __syncthreads();
    if (threadIdx.x == 0) *flag = (red == 0u) ? 1 : 0;
}

__global__ __launch_bounds__(256) void edge_fallback_kernel(
    const float* __restrict__ z, const void* __restrict__ ei,
    const int* __restrict__ flag, const float* __restrict__ W1l,
    const float* __restrict__ b1l, const float* __restrict__ W1r,
    const float* __restrict__ b1r, const float* __restrict__ W2,
    const float* __restrict__ b2, float* __restrict__ out) {
    __shared__ f4 Wl4[64 * 32];
    __shared__ f4 Wr4[64 * 32];
    const int tid = threadIdx.x;
    #pragma unroll
    for (int i = 0; i < 8; ++i) {
        int gg = tid + i * 256;
        int h = gg >> 5, v = gg & 31;
        int slot = (h << 5) | (v ^ (h & 7));
        Wl4[slot] = ((const f4*)W1l)[gg];
        Wr4[slot] = ((const f4*)W1r)[gg];
    }
    __syncthreads();
    const int wave = tid >> 6, lane = tid & 63;
    int e = blockIdx.x * 4 + wave;
    if (e >= N_EDGES) return;
    const int is64 = (flag != nullptr) ? *flag : 0;
    int src = load_idx(ei, is64, e);
    int dst = load_idx(ei, is64, N_EDGES + e);
    float accl = 0.f, accr = 0.f;
    #pragma unroll 4
    for (int v = 0; v < 32; ++v) {
        f4 wl = Wl4[(lane << 5) | (v ^ (lane & 7))];
        f4 wr = Wr4[(lane << 5) | (v ^ (lane & 7))];
        f4 zl = ((const f4*)z)[src * 32 + v];
        f4 zr = ((const f4*)z)[dst * 32 + v];
        accl += wl.x * zl.x + wl.y * zl.y + wl.z * zl.z + wl.w * zl.w;
        accr += wr.x * zr.x + wr.y * zr.y + wr.z * zr.z + wr.w * zr.w;
    }
    float h = lrelu(accl + b1l[lane] + accr + b1r[lane]) * W2[lane];
    #pragma unroll
    for (int off = 32; off; off >>= 1) h += __shfl_xor(h, off, 64);
    if (lane == 0) out[e] = 1.f / (1.f + __expf(-(h + b2[0])));
}

extern "C" void kernel_launch(void* const* d_in, const int* in_sizes, int n_in,
                              void* d_out, int out_size, void* d_ws,
                              size_t ws_size, hipStream_t stream) {
    const float* z   = (const float*)d_in[0];
    const void*  ei  = d_in[1];
    const float* W1l = (const float*)d_in[2];
    const float* b1l = (const float*)d_in[3];
    const float* W1r = (const float*)d_in[4];
    const float* b1r = (const float*)d_in[5];
    const float* W2  = (const float*)d_in[6];
    const float* b2  = (const float*)d_in[7];
    float* out = (float*)d_out;

    const size_t pcomb_bytes = (size_t)N_NODES * 128 * sizeof(u16);  // 25.6 MB
    const size_t need = pcomb_bytes + 256;

    if (ws_size >= need) {
        u16* pcomb = (u16*)d_ws;
        int* flag = (int*)((char*)d_ws + pcomb_bytes);

        // size cooperative grid to co-residency (host-side queries: capture-safe)
        int maxB = 0, nCU = 0, dev = 0;
        hipGetDevice(&dev);
        hipDeviceGetAttribute(&nCU, hipDeviceAttributeMultiprocessorCount, dev);
        hipOccupancyMaxActiveBlocksPerMultiprocessor(&maxB, fused_kernel, 256, 0);
        int grid = (maxB > 0 && nCU > 0) ? maxB * nCU : 0;

        hipError_t e = hipErrorUnknown;
        if (grid >= 64) {
            void* args[] = {(void*)&z,  (void*)&W1l, (void*)&b1l, (void*)&W1r,
                            (void*)&b1r, (void*)&ei, (void*)&W2,  (void*)&b2,
                            (void*)&out, (void*)&pcomb};
            e = hipLaunchCooperativeKernel((const void*)fused_kernel, dim3(grid),
                                           dim3(256), args, 0, stream);
        }
        if (e != hipSuccess) {
            // proven two-kernel path
            node_proj_kernel<<<(N_NODES + 63) / 64, 256, 0, stream>>>(
                z, W1l, b1l, W1r, b1r, (const u32*)ei, flag, pcomb);
            edge_quad_kernel<<<(N_EDGES / 4 * 8 + 255) / 256, 256, 0, stream>>>(
                ei, flag, pcomb, W2, b2, out);
        }
    } else if (ws_size >= 256) {
        int* flag = (int*)d_ws;
        detect_idx_kernel<<<1, 256, 0, stream>>>((const u32*)ei, flag);
        edge_fallback_kernel<<<(N_EDGES + 3) / 4, 256, 0, stream>>>(
            z, ei, flag, W1l, b1l, W1r, b1r, W2, b2, out);
    } else {
        edge_fallback_kernel<<<(N_EDGES + 3) / 4, 256, 0, stream>>>(
            z, ei, nullptr, W1l, b1l, W1r, b1r, W2, b2, out);
    }
}

// Round 6
// 47.291 us; speedup vs baseline: 2.2269x; 2.2269x over previous
//
#include <hip/hip_runtime.h>
#include <math.h>

#define N_NODES 100000
#define N_EDGES 600000
#define IN_CH 128
#define HID 64
#define NEG_SLOPE 0.01f
#define NP_GRID 1024

typedef float4 f4;
typedef unsigned short u16;
typedef unsigned int u32;
typedef __attribute__((ext_vector_type(8))) short bf16x8;   // 8 bf16 (4 VGPRs)
typedef __attribute__((ext_vector_type(4))) float f32x4;    // MFMA acc

__device__ __forceinline__ float lrelu(float x) {
    return fmaxf(x, NEG_SLOPE * x);
}
__device__ __forceinline__ float uasf(u32 w) { return __uint_as_float(w); }

// HW packed conversion: one VALU op for 2 f32 -> packed bf16.
__device__ __forceinline__ u32 cvt_pk(float lo, float hi) {
    u32 r;
    asm("v_cvt_pk_bf16_f32 %0, %1, %2" : "=v"(r) : "v"(lo), "v"(hi));
    return r;
}

__device__ __forceinline__ int load_idx(const void* ei, int is64, int pos) {
    if (is64) return (int)((const long long*)ei)[pos];
    return ((const int*)ei)[pos];
}

// shared edge dot: 8 bf16 pairs vs W2 chunk
__device__ __forceinline__ float edot(uint4 a, uint4 b, f4 w0, f4 w1) {
    float s;
    s  = lrelu(uasf(a.x << 16) + uasf(b.x << 16)) * w0.x;
    s += lrelu(uasf(a.x & 0xffff0000u) + uasf(b.x & 0xffff0000u)) * w0.y;
    s += lrelu(uasf(a.y << 16) + uasf(b.y << 16)) * w0.z;
    s += lrelu(uasf(a.y & 0xffff0000u) + uasf(b.y & 0xffff0000u)) * w0.w;
    s += lrelu(uasf(a.z << 16) + uasf(b.z << 16)) * w1.x;
    s += lrelu(uasf(a.z & 0xffff0000u) + uasf(b.z & 0xffff0000u)) * w1.y;
    s += lrelu(uasf(a.w << 16) + uasf(b.w << 16)) * w1.z;
    s += lrelu(uasf(a.w & 0xffff0000u) + uasf(b.w & 0xffff0000u)) * w1.w;
    return s;
}

// ---------------------------------------------------------------------------
// Node projection v2 (round-6 restructure, theory: W-LDS had ZERO reuse and
// its 32 KB capped occupancy at 12 waves/CU).
//   - W fragments live in REGISTERS: wf[c2][kk], 8 x bf16x8 = 32 VGPR, loaded
//     once per block, reused across ~1.5 grid-stride tiles.
//   - LDS holds only the z tile (16.5 KB) -> 4 blocks/CU if VGPR <= 128.
//   - Orientation invariants unchanged (verified rounds 3-5, absmax 3.9e-3):
//     acc = mfma(W_frag, z_frag, acc); z-row (n4*16+m) -> D col m = node;
//     W-row R (R&15==m) -> D row 4g+j = h R0+4g+j; shared K bijection
//     gran=(kk<<2)|g; zt swizzle slot (row<<4)|(gr^(row&15)) -> 0 conflicts.
// Block 0 additionally detects int32 vs int64 edge_index into *flag.
// ---------------------------------------------------------------------------
__global__ __launch_bounds__(256) void node_proj_v2(
    const float* __restrict__ z, const float* __restrict__ W1l,
    const float* __restrict__ b1l, const float* __restrict__ W1r,
    const float* __restrict__ b1r, const u32* __restrict__ ei_words,
    int* __restrict__ flag, u16* __restrict__ pcomb) {
    __shared__ uint4 zt[64 * 16];   // 16 KB
    __shared__ u32 red;

    const int tid = threadIdx.x;

    if (blockIdx.x == 0) {  // is64 detect: high words of first 2048 entries
        if (tid == 0) red = 0u;
        __syncthreads();
        u32 acc = 0u;
        #pragma unroll
        for (int i = 0; i < 8; ++i)
            acc |= ei_words[(i * 256 + tid) * 2 + 1];
        atomicOr(&red, acc);
        __syncthreads();
        if (tid == 0) *flag = (red == 0u) ? 1 : 0;
    }

    const int wave = tid >> 6, lane = tid & 63;
    const int m = lane & 15, g = lane >> 4;

    // ---- W fragments -> registers (once per block; L2-resident after start)
    bf16x8 wf[2][4];
    #pragma unroll
    for (int c2 = 0; c2 < 2; ++c2) {
        const int R = (wave << 5) + (c2 << 4) + m;   // R & 15 == m
        const float* wsrc = (R < 64) ? (W1l + R * IN_CH)
                                     : (W1r + (R - 64) * IN_CH);
        #pragma unroll
        for (int kk = 0; kk < 4; ++kk) {
            const int gran = (kk << 2) | g;
            f4 a = ((const f4*)wsrc)[gran * 2];
            f4 b = ((const f4*)wsrc)[gran * 2 + 1];
            uint4 p;
            p.x = cvt_pk(a.x, a.y); p.y = cvt_pk(a.z, a.w);
            p.z = cvt_pk(b.x, b.y); p.w = cvt_pk(b.z, b.w);
            wf[c2][kk] = *(const bf16x8*)&p;
        }
    }

    // bias vectors for this thread's output columns (wave-constant halves)
    const int colbase = wave << 5;
    f4 bb[2];
    #pragma unroll
    for (int c2 = 0; c2 < 2; ++c2) {
        const int col0 = colbase + (c2 << 4) + (g << 2);
        bb[c2] = *(const f4*)((colbase < 64) ? (b1l + col0) : (b1r + col0 - 64));
    }

    const int ntiles = (N_NODES + 63) / 64;  // 1563
    for (int tile = blockIdx.x; tile < ntiles; tile += NP_GRID) {
        const int base = tile * 64;
        __syncthreads();   // previous tile's readers done -> zt reusable
        #pragma unroll
        for (int i = 0; i < 4; ++i) {
            int gidx = tid + i * 256;
            int row = gidx >> 4, gr = gidx & 15;
            int node = base + row;
            if (node >= N_NODES) node = N_NODES - 1;  // pad reads
            f4 a = ((const f4*)z)[node * 32 + gr * 2];
            f4 b = ((const f4*)z)[node * 32 + gr * 2 + 1];
            uint4 p;
            p.x = cvt_pk(a.x, a.y); p.y = cvt_pk(a.z, a.w);
            p.z = cvt_pk(b.x, b.y); p.w = cvt_pk(b.z, b.w);
            zt[(row << 4) | (gr ^ (row & 15))] = p;
        }
        __syncthreads();

        f32x4 acc[4][2];
        #pragma unroll
        for (int n4 = 0; n4 < 4; ++n4)
            #pragma unroll
            for (int c2 = 0; c2 < 2; ++c2) acc[n4][c2] = {0.f, 0.f, 0.f, 0.f};

        #pragma unroll
        for (int kk = 0; kk < 4; ++kk) {
            const int gran = (kk << 2) | g;
            bf16x8 zf[4];
            #pragma unroll
            for (int n4 = 0; n4 < 4; ++n4)
                zf[n4] = *(const bf16x8*)&zt[(((n4 << 4) | m) << 4) | (gran ^ m)];
            #pragma unroll
            for (int n4 = 0; n4 < 4; ++n4)
                #pragma unroll
                for (int c2 = 0; c2 < 2; ++c2)
                    acc[n4][c2] = __builtin_amdgcn_mfma_f32_16x16x32_bf16(
                        wf[c2][kk], zf[n4], acc[n4][c2], 0, 0, 0);
        }

        #pragma unroll
        for (int c2 = 0; c2 < 2; ++c2) {
            const int col0 = colbase + (c2 << 4) + (g << 2);
            #pragma unroll
            for (int n4 = 0; n4 < 4; ++n4) {
                int node = base + (n4 << 4) + m;
                if (node < N_NODES) {
                    uint2 v;
                    v.x = cvt_pk(acc[n4][c2][0] + bb[c2].x,
                                 acc[n4][c2][1] + bb[c2].y);
                    v.y = cvt_pk(acc[n4][c2][2] + bb[c2].z,
                                 acc[n4][c2][3] + bb[c2].w);
                    *(uint2*)(pcomb + (size_t)node * 128 + col0) = v;
                }
            }
        }
    }
}

// ---------------------------------------------------------------------------
// Edge kernel (round-4 proven): 8 lanes per quad of 4 edges; lane c gathers
// 16B chunk c of pl[src] / 8+c of pr[dst]; 8 gathers in flight; float4 out.
// ---------------------------------------------------------------------------
__global__ __launch_bounds__(256) void edge_quad_kernel(
    const void* __restrict__ ei, const int* __restrict__ flag,
    const u16* __restrict__ pcomb, const float* __restrict__ W2,
    const float* __restrict__ b2, float* __restrict__ out) {
    int t = blockIdx.x * 256 + threadIdx.x;
    int q = t >> 3;
    int c = t & 7;
    if (q >= N_EDGES / 4) return;
    const int is64 = *flag;
    int s[4], d[4];
    if (is64) {
        const longlong2* p = (const longlong2*)ei;
        longlong2 p0 = p[2 * q], p1 = p[2 * q + 1];
        longlong2 q0 = p[N_EDGES / 2 + 2 * q], q1 = p[N_EDGES / 2 + 2 * q + 1];
        s[0] = (int)p0.x; s[1] = (int)p0.y; s[2] = (int)p1.x; s[3] = (int)p1.y;
        d[0] = (int)q0.x; d[1] = (int)q0.y; d[2] = (int)q1.x; d[3] = (int)q1.y;
    } else {
        int4 sp = ((const int4*)ei)[q];
        int4 dp = ((const int4*)ei)[N_EDGES / 4 + q];
        s[0] = sp.x; s[1] = sp.y; s[2] = sp.z; s[3] = sp.w;
        d[0] = dp.x; d[1] = dp.y; d[2] = dp.z; d[3] = dp.w;
    }
    const uint4* pc4 = (const uint4*)pcomb;
    uint4 a0 = pc4[s[0] * 16 + c],     a1 = pc4[s[1] * 16 + c];
    uint4 a2 = pc4[s[2] * 16 + c],     a3 = pc4[s[3] * 16 + c];
    uint4 e0 = pc4[d[0] * 16 + 8 + c], e1 = pc4[d[1] * 16 + 8 + c];
    uint4 e2 = pc4[d[2] * 16 + 8 + c], e3 = pc4[d[3] * 16 + 8 + c];
    f4 w0 = ((const f4*)W2)[c * 2];
    f4 w1 = ((const f4*)W2)[c * 2 + 1];
    float r0 = edot(a0, e0, w0, w1);
    float r1 = edot(a1, e1, w0, w1);
    float r2 = edot(a2, e2, w0, w1);
    float r3 = edot(a3, e3, w0, w1);
    #pragma unroll
    for (int off = 4; off; off >>= 1) {
        r0 += __shfl_xor(r0, off, 8);
        r1 += __shfl_xor(r1, off, 8);
        r2 += __shfl_xor(r2, off, 8);
        r3 += __shfl_xor(r3, off, 8);
    }
    if (c == 0) {
        float bbs = b2[0];
        f4 o;
        o.x = 1.f / (1.f + __expf(-(r0 + bbs)));
        o.y = 1.f / (1.f + __expf(-(r1 + bbs)));
        o.z = 1.f / (1.f + __expf(-(r2 + bbs)));
        o.w = 1.f / (1.f + __expf(-(r3 + bbs)));
        *(f4*)(out + q * 4) = o;
    }
}

// ---------------------------------------------------------------------------
// Tiny-workspace fallbacks (proven)
// ---------------------------------------------------------------------------
__global__ void detect_idx_kernel(const u32* __restrict__ ei_words,
                                  int* __restrict__ flag) {
    __shared__ u32 red;
    if (threadIdx.x == 0) red = 0u;
    __syncthreads();
    u32 acc = 0u;
    #pragma unroll
    for (int i = 0; i < 8; ++i)
        acc |= ei_words[(i * 256 + threadIdx.x) * 2 + 1];
    atomicOr(&red, acc);
    __syncthreads();
    if (threadIdx.x == 0) *flag = (red == 0u) ? 1 : 0;
}

__global__ __launch_bounds__(256) void edge_fallback_kernel(
    const float* __restrict__ z, const void* __restrict__ ei,
    const int* __restrict__ flag, const float* __restrict__ W1l,
    const float* __restrict__ b1l, const float* __restrict__ W1r,
    const float* __restrict__ b1r, const float* __restrict__ W2,
    const float* __restrict__ b2, float* __restrict__ out) {
    __shared__ f4 Wl4[64 * 32];
    __shared__ f4 Wr4[64 * 32];
    const int tid = threadIdx.x;
    #pragma unroll
    for (int i = 0; i < 8; ++i) {
        int gg = tid + i * 256;
        int h = gg >> 5, v = gg & 31;
        int slot = (h << 5) | (v ^ (h & 7));
        Wl4[slot] = ((const f4*)W1l)[gg];
        Wr4[slot] = ((const f4*)W1r)[gg];
    }
    __syncthreads();
    const int wave = tid >> 6, lane = tid & 63;
    int e = blockIdx.x * 4 + wave;
    if (e >= N_EDGES) return;
    const int is64 = (flag != nullptr) ? *flag : 0;
    int src = load_idx(ei, is64, e);
    int dst = load_idx(ei, is64, N_EDGES + e);
    float accl = 0.f, accr = 0.f;
    #pragma unroll 4
    for (int v = 0; v < 32; ++v) {
        f4 wl = Wl4[(lane << 5) | (v ^ (lane & 7))];
        f4 wr = Wr4[(lane << 5) | (v ^ (lane & 7))];
        f4 zl = ((const f4*)z)[src * 32 + v];
        f4 zr = ((const f4*)z)[dst * 32 + v];
        accl += wl.x * zl.x + wl.y * zl.y + wl.z * zl.z + wl.w * zl.w;
        accr += wr.x * zr.x + wr.y * zr.y + wr.z * zr.z + wr.w * zr.w;
    }
    float h = lrelu(accl + b1l[lane] + accr + b1r[lane]) * W2[lane];
    #pragma unroll
    for (int off = 32; off; off >>= 1) h += __shfl_xor(h, off, 64);
    if (lane == 0) out[e] = 1.f / (1.f + __expf(-(h + b2[0])));
}

extern "C" void kernel_launch(void* const* d_in, const int* in_sizes, int n_in,
                              void* d_out, int out_size, void* d_ws,
                              size_t ws_size, hipStream_t stream) {
    const float* z   = (const float*)d_in[0];
    const void*  ei  = d_in[1];
    const float* W1l = (const float*)d_in[2];
    const float* b1l = (const float*)d_in[3];
    const float* W1r = (const float*)d_in[4];
    const float* b1r = (const float*)d_in[5];
    const float* W2  = (const float*)d_in[6];
    const float* b2  = (const float*)d_in[7];
    float* out = (float*)d_out;

    const size_t pcomb_bytes = (size_t)N_NODES * 128 * sizeof(u16);  // 25.6 MB
    const size_t need = pcomb_bytes + 256;

    if (ws_size >= need) {
        u16* pcomb = (u16*)d_ws;
        int* flag = (int*)((char*)d_ws + pcomb_bytes);
        node_proj_v2<<<NP_GRID, 256, 0, stream>>>(
            z, W1l, b1l, W1r, b1r, (const u32*)ei, flag, pcomb);
        edge_quad_kernel<<<(N_EDGES / 4 * 8 + 255) / 256, 256, 0, stream>>>(
            ei, flag, pcomb, W2, b2, out);
    } else if (ws_size >= 256) {
        int* flag = (int*)d_ws;
        detect_idx_kernel<<<1, 256, 0, stream>>>((const u32*)ei, flag);
        edge_fallback_kernel<<<(N_EDGES + 3) / 4, 256, 0, stream>>>(
            z, ei, flag, W1l, b1l, W1r, b1r, W2, b2, out);
    } else {
        edge_fallback_kernel<<<(N_EDGES + 3) / 4, 256, 0, stream>>>(
            z, ei, nullptr, W1l, b1l, W1r, b1r, W2, b2, out);
    }
}